// Round 13
// baseline (2496.570 us; speedup 1.0000x reference)
//
#include <hip/hip_runtime.h>
#include <hip/hip_bf16.h>
#include <stdint.h>
#include <stddef.h>

#define T_LEN 512
#define B_SZ  256
#define I_SZ  256
#define H_SZ  1024

typedef __attribute__((ext_vector_type(8))) short bf16x8;
typedef __attribute__((ext_vector_type(4))) float f32x4;
typedef __attribute__((ext_vector_type(4))) unsigned int u32x4;
typedef unsigned short u16;
typedef unsigned int   u32;
typedef unsigned long long u64;

__device__ inline u16 f2bf(float f) {
  union { float f; u32 u; } x; x.f = f;
  u32 r = x.u + 0x7fffu + ((x.u >> 16) & 1u);
  return (u16)(r >> 16);
}
__device__ inline u32 bf2pk(u32 a, u32 b) {  // two fp32 bit-patterns -> packed bf16x2
  u32 ra = (a + 0x7fffu + ((a >> 16) & 1u)) >> 16;
  u32 rb = (b + 0x7fffu + ((b >> 16) & 1u)) >> 16;
  return ra | (rb << 16);
}

// keep 8 bf16x8 values pinned in VGPRs (0 instructions)
#define PIN8(B, i) asm volatile("" : "+v"(B[i]), "+v"(B[i+1]), "+v"(B[i+2]), \
    "+v"(B[i+3]), "+v"(B[i+4]), "+v"(B[i+5]), "+v"(B[i+6]), "+v"(B[i+7]))
#define PIN32(B) do { PIN8(B,0); PIN8(B,8); PIN8(B,16); PIN8(B,24); } while (0)

__global__ __launch_bounds__(256) void cvt_kernel(const float* __restrict__ src,
                                                  u16* __restrict__ dst, int n) {
  int stride = gridDim.x * blockDim.x * 4;
  for (int i = (blockIdx.x * blockDim.x + threadIdx.x) * 4; i < n; i += stride) {
    float4 v = *reinterpret_cast<const float4*>(src + i);
    ushort4 o;
    o.x = f2bf(v.x); o.y = f2bf(v.y); o.z = f2bf(v.z); o.w = f2bf(v.w);
    *reinterpret_cast<ushort4*>(dst + i) = o;
  }
}

// Persistent fused CTRNN with IN-BAND tagged hand-off (barrier-free).
// h >= 0 always (ReLU blend from h0=0), so bf16 sign bits are free: the
// producer's 8B atomic store carries a step-parity tag in bit 15 (sign of the
// group's first bf16). Consumers poll THEIR OWN staging u64s via proven
// __hip_atomic_load(AGENT) until all tags match ((t>>1)&1 — distinguishes
// fresh data from the 2-steps-stale value in the ping-pong buffer), clear the
// bits, ds_write. No counters, no leader poll, no release barrier.
// Overwrite-WAR is safe transitively: P's step-(t+2) store requires P to have
// observed C's step-(t+1) store, which data-depends on C's step-(t+1) read.
__global__ __launch_bounds__(256, 1) void rnn_persistent(
    const float* __restrict__ x, const u16* __restrict__ Win,
    const u16* __restrict__ Whh, const float* __restrict__ b_in,
    const float* __restrict__ b_hh, float* __restrict__ out,
    u16* __restrict__ hb0, u16* __restrict__ hb1) {
  __shared__ __align__(16) u16 As[16 * 1024];      // 32KB h tile, swizzled
  __shared__ __align__(16) u16 Xs[2][16 * 256];    // 2 x 8KB x tiles, swizzled

  const int b   = blockIdx.x;
  const int mg  = ((b & 7) << 1) | ((b >> 3) & 1);  // batch-group
  const int ng  = b >> 4;                           // col-group
  const int bm0 = mg * 16;
  const int bn0 = ng * 64;
  const int tid = threadIdx.x, lane = tid & 63, wid = tid >> 6;
  const int rl  = lane & 15, kq = lane >> 4;

  // W fragments in registers: W_hh 16 cols x K=1024 + W_in K=256
  const int wcol = bn0 + wid * 16 + rl;
  bf16x8 Breg[32];
#pragma unroll
  for (int kc = 0; kc < 32; ++kc)
    Breg[kc] = *reinterpret_cast<const bf16x8*>(Whh + (size_t)wcol * H_SZ + kc * 32 + kq * 8);
  bf16x8 Wreg[8];
#pragma unroll
  for (int kc = 0; kc < 8; ++kc)
    Wreg[kc] = *reinterpret_cast<const bf16x8*>(Win + (size_t)wcol * I_SZ + kc * 32 + kq * 8);
  PIN32(Breg);
  PIN8(Wreg, 0);

  const int row = bm0 + rl;                  // batch row (D col dim)
  const int c0  = bn0 + wid * 16 + kq * 4;   // 4 consecutive hidden cols (D rows)
  float4 bsum;
#pragma unroll
  for (int r = 0; r < 4; ++r)
    (&bsum.x)[r] = b_in[c0 + r] + b_hh[c0 + r];

  float4 hprev = {0.f, 0.f, 0.f, 0.f};
  const char* Asb = (const char*)As;

  const int wb = (tid & 127) * 16;  // h-stage: in-row byte offset
  const int rb = tid >> 7;          // h-stage: row parity

  const int xc0 = tid * 2;          // x tile: 2 chunks/thread

  // prologue: stage x tile for step 0
  {
    const float* xs = x;
#pragma unroll
    for (int j = 0; j < 2; ++j) {
      int c  = xc0 + j;
      int r_ = c >> 5;
      int cb = (c & 31) * 16;
      const float* src = xs + (size_t)(bm0 + r_) * I_SZ + (c & 31) * 8;
      float4 f0 = *reinterpret_cast<const float4*>(src);
      float4 f1 = *reinterpret_cast<const float4*>(src + 4);
      u32x4 v;
      v.x = (u32)f2bf(f0.x) | ((u32)f2bf(f0.y) << 16);
      v.y = (u32)f2bf(f0.z) | ((u32)f2bf(f0.w) << 16);
      v.z = (u32)f2bf(f1.x) | ((u32)f2bf(f1.y) << 16);
      v.w = (u32)f2bf(f1.z) | ((u32)f2bf(f1.w) << 16);
      int dst = r_ * 512 + (cb ^ ((r_ & 7) << 4));
      *reinterpret_cast<u32x4*>((char*)Xs[0] + dst) = v;
    }
  }
  __syncthreads();

  for (int t = 0; t < T_LEN; ++t) {
    const u16* hin = (t & 1) ? hb1 : hb0;
    u16* hout      = (t & 1) ? hb0 : hb1;

    PIN32(Breg);

    // ---- 1. issue poll loads FIRST (tag-check then waits vmcnt(4), not on x)
    u64 pv[16];
    const char* hinb = (const char*)hin;
#pragma unroll
    for (int i = 0; i < 8; ++i) {
      const u64* p = reinterpret_cast<const u64*>(
          hinb + (size_t)(bm0 + 2 * i + rb) * 2048 + wb);
      pv[2 * i]     = __hip_atomic_load(p,     __ATOMIC_RELAXED, __HIP_MEMORY_SCOPE_AGENT);
      pv[2 * i + 1] = __hip_atomic_load(p + 1, __ATOMIC_RELAXED, __HIP_MEMORY_SCOPE_AGENT);
    }

    // ---- 2. x loads for t+1 (plain, compiler-visible; consumed in the tail)
    float4 xf0a, xf0b, xf1a, xf1b;
    if (t < T_LEN - 1) {
      const float* xs = x + (size_t)(t + 1) * (B_SZ * I_SZ);
      {
        int c = xc0, r_ = c >> 5;
        const float* src = xs + (size_t)(bm0 + r_) * I_SZ + (c & 31) * 8;
        xf0a = *reinterpret_cast<const float4*>(src);
        xf0b = *reinterpret_cast<const float4*>(src + 4);
      }
      {
        int c = xc0 + 1, r_ = c >> 5;
        const float* src = xs + (size_t)(bm0 + r_) * I_SZ + (c & 31) * 8;
        xf1a = *reinterpret_cast<const float4*>(src);
        xf1b = *reinterpret_cast<const float4*>(src + 4);
      }
    }

    // ---- 3. acc2 (x-tile MFMA) under the poll-load flight
    f32x4 acc2 = (f32x4){0.f, 0.f, 0.f, 0.f};
    {
      const char* Xb = (const char*)Xs[t & 1];
#pragma unroll
      for (int kc = 0; kc < 8; ++kc) {
        bf16x8 xa = *reinterpret_cast<const bf16x8*>(
            Xb + rl * 512 + ((kc * 64 + kq * 16) ^ ((rl & 7) << 4)));
        acc2 = __builtin_amdgcn_mfma_f32_16x16x32_bf16(Wreg[kc], xa, acc2, 0, 0, 0);
      }
    }

    // ---- 4. tag check + retry (proven atomic loads; per-lane divergent exit)
    const u64 want = ((u64)((t >> 1) & 1)) << 15;
    for (;;) {
      u64 bad = 0;
#pragma unroll
      for (int i = 0; i < 16; ++i) bad |= (pv[i] ^ want) & 0x8000ull;
      if (bad == 0) break;
      __builtin_amdgcn_s_sleep(1);
#pragma unroll
      for (int i = 0; i < 8; ++i) {
        const u64* p = reinterpret_cast<const u64*>(
            hinb + (size_t)(bm0 + 2 * i + rb) * 2048 + wb);
        pv[2 * i]     = __hip_atomic_load(p,     __ATOMIC_RELAXED, __HIP_MEMORY_SCOPE_AGENT);
        pv[2 * i + 1] = __hip_atomic_load(p + 1, __ATOMIC_RELAXED, __HIP_MEMORY_SCOPE_AGENT);
      }
    }

    // ---- 5. clear tags, swizzled ds_write
#pragma unroll
    for (int i = 0; i < 8; ++i) {
      int r_ = 2 * i + rb;
      u64 a = pv[2 * i]     & ~0x8000ull;
      u64 c = pv[2 * i + 1] & ~0x8000ull;
      u32x4 v;
      v.x = (u32)a; v.y = (u32)(a >> 32);
      v.z = (u32)c; v.w = (u32)(c >> 32);
      int dst = r_ * 2048 + (wb ^ ((r_ & 7) << 4));
      *reinterpret_cast<u32x4*>((char*)As + dst) = v;
    }
    __syncthreads();

    PIN32(Breg);

    // ---- 6. MFMA: D = W_hh x h^T
    f32x4 acc0 = (f32x4){0.f, 0.f, 0.f, 0.f};
    f32x4 acc1 = (f32x4){0.f, 0.f, 0.f, 0.f};
#pragma unroll
    for (int kc = 0; kc < 32; kc += 2) {
      bf16x8 a0 = *reinterpret_cast<const bf16x8*>(
          Asb + rl * 2048 + ((kc * 64 + kq * 16) ^ ((rl & 7) << 4)));
      acc0 = __builtin_amdgcn_mfma_f32_16x16x32_bf16(Breg[kc], a0, acc0, 0, 0, 0);
      bf16x8 a1 = *reinterpret_cast<const bf16x8*>(
          Asb + rl * 2048 + (((kc + 1) * 64 + kq * 16) ^ ((rl & 7) << 4)));
      acc1 = __builtin_amdgcn_mfma_f32_16x16x32_bf16(Breg[kc + 1], a1, acc1, 0, 0, 0);
    }

    // ---- 7. epilogue: compute h; tagged 8B atomic store = data + signal
    float hv[4];
#pragma unroll
    for (int r = 0; r < 4; ++r) {
      float pre = acc0[r] + acc1[r] + acc2[r] + (&bsum.x)[r];
      float hn  = fmaxf(pre, 0.f);
      float h   = (&hprev.x)[r] * 0.9f + hn * 0.1f;
      (&hprev.x)[r] = h;
      hv[r] = h;
    }
    if (t < T_LEN - 1) {
      u32 lo = (u32)f2bf(hv[0]) | ((u32)f2bf(hv[1]) << 16);
      u32 hi = (u32)f2bf(hv[2]) | ((u32)f2bf(hv[3]) << 16);
      lo |= ((u32)(((t + 1) >> 1) & 1)) << 15;   // parity tag in sign of bf16 #0
      u64 pk = (u64)lo | ((u64)hi << 32);
      __hip_atomic_store(reinterpret_cast<u64*>(hout + (size_t)row * H_SZ + c0),
                         pk, __ATOMIC_RELAXED, __HIP_MEMORY_SCOPE_AGENT);
    }

    // ---- 8. off-critical-path: fp32 out stores, x cvt + Xs[(t+1)&1] write
    float4 ho = {hv[0], hv[1], hv[2], hv[3]};
    *reinterpret_cast<float4*>(out + (size_t)t * (B_SZ * H_SZ) +
                               (size_t)row * H_SZ + c0) = ho;
    if (t == T_LEN - 1)
      *reinterpret_cast<float4*>(out + (size_t)T_LEN * (B_SZ * H_SZ) +
                                 (size_t)row * H_SZ + c0) = ho;

    if (t < T_LEN - 1) {
      char* Xw = (char*)Xs[(t + 1) & 1];
      union { float4 f; u32x4 u; } a0u, a1u, b0u, b1u;
      a0u.f = xf0a; a1u.f = xf0b; b0u.f = xf1a; b1u.f = xf1b;
      {
        int c = xc0, r_ = c >> 5, cb = (c & 31) * 16;
        u32x4 v;
        v.x = bf2pk(a0u.u.x, a0u.u.y); v.y = bf2pk(a0u.u.z, a0u.u.w);
        v.z = bf2pk(a1u.u.x, a1u.u.y); v.w = bf2pk(a1u.u.z, a1u.u.w);
        int dst = r_ * 512 + (cb ^ ((r_ & 7) << 4));
        *reinterpret_cast<u32x4*>(Xw + dst) = v;
      }
      {
        int c = xc0 + 1, r_ = c >> 5, cb = (c & 31) * 16;
        u32x4 v;
        v.x = bf2pk(b0u.u.x, b0u.u.y); v.y = bf2pk(b0u.u.z, b0u.u.w);
        v.z = bf2pk(b1u.u.x, b1u.u.y); v.w = bf2pk(b1u.u.z, b1u.u.w);
        int dst = r_ * 512 + (cb ^ ((r_ & 7) << 4));
        *reinterpret_cast<u32x4*>(Xw + dst) = v;
      }
    }

    __syncthreads();   // LDS WAR: As/Xs reads done before next step's writes
  }
}

extern "C" void kernel_launch(void* const* d_in, const int* in_sizes, int n_in,
                              void* d_out, int out_size, void* d_ws, size_t ws_size,
                              hipStream_t stream) {
  const float* x    = (const float*)d_in[0];
  const float* W_in = (const float*)d_in[1];
  const float* b_in = (const float*)d_in[2];
  const float* W_hh = (const float*)d_in[3];
  const float* b_hh = (const float*)d_in[4];
  float* out = (float*)d_out;

  // workspace layout (bytes) — no overlaps
  const size_t off_wib = 0;             // 1024*256  bf16 = 524288
  const size_t off_whb = 524288;        // 1024*1024 bf16 = 2097152
  const size_t off_hb0 = 2621440;       // 256*1024  bf16 = 524288
  const size_t off_hb1 = 3145728;
  const size_t need    = 3670016;
  if (ws_size < need) return;

  char* ws = (char*)d_ws;
  u16* wib = (u16*)(ws + off_wib);
  u16* whb = (u16*)(ws + off_whb);
  u16* hb0 = (u16*)(ws + off_hb0);
  u16* hb1 = (u16*)(ws + off_hb1);

  cvt_kernel<<<64,  256, 0, stream>>>(W_in, wib, H_SZ * I_SZ);
  cvt_kernel<<<256, 256, 0, stream>>>(W_hh, whb, H_SZ * H_SZ);
  // hb0 must be zero (tag 0 = expected at t=0) EVERY launch: in-graph memset
  hipMemsetAsync(hb0, 0, (size_t)B_SZ * H_SZ * sizeof(u16), stream);

  rnn_persistent<<<256, 256, 0, stream>>>(x, wib, whb, b_in, b_hh,
                                          out, hb0, hb1);
}